// Round 17
// baseline (98.435 us; speedup 1.0000x reference)
//
#include <hip/hip_runtime.h>
#include <math.h>

#define NB   4
#define CIN  512
#define HID  64
#define NK   11     // NUM_CLASSES+1
#define HH1  60
#define W1p  80
#define P1   4800
#define HH2  30
#define W2p  40
#define P2   1200
#define HO   480
#define WOp  640
#define NP1  (NB*P1)    // 19200
#define NP2  (NB*P2)    // 4800
#define PLANE ((size_t)HO*WOp)                  // 307200
#define SEG_OFF ((size_t)NB*NK*PLANE)           // 13,516,800
#define BBX_OFF (SEG_OFF + (size_t)NB*PLANE)    // 14,745,600

// ws layout in floats. Packed bf16 W-fragments: 2 convs x 2 planes x 32768
// ushort = 131072 ushort = 65536 floats.
#define WS_C1  65536                            // 19200*64 = 1,228,800
#define WS_F2  (WS_C1 + NP1*64)                 // 4800*64  =   307,200
#define WS_PRB (WS_F2 + NP2*64)                 // 19200*12 =   230,400
#define WS_SEG (WS_PRB + NP1*12)                // 19200 ints

typedef __attribute__((ext_vector_type(8))) short bf16x8;
typedef __attribute__((ext_vector_type(4))) float f32x4;

// RNE fp32 -> bf16, returns bits, writes residual x - bf16(x)
__device__ __forceinline__ unsigned short bfsplit(float x, float& resid) {
    unsigned u = __float_as_uint(x);
    unsigned t = u + 0x7FFFu + ((u >> 16) & 1u);
    unsigned short h = (unsigned short)(t >> 16);
    resid = x - __uint_as_float((unsigned)h << 16);
    return h;
}

// -------- pack weights into chunk-major A-fragment pages, 2-plane split -----
// (identical to r13, end-to-end verified at absmax 3.9e-3)
__global__ __launch_bounds__(256) void pack_w(const float* __restrict__ w1,
                                              const float* __restrict__ w2,
                                              float* __restrict__ ws) {
    int i = blockIdx.x * 256 + threadIdx.x;   // 0..32767
    if (i >= HID * CIN) return;
    int o = i >> 9, c = i & 511;
    int chunk = c >> 6, r = c & 63, ks2 = r >> 5, k = r & 31;
    int lane = (o & 15) + ((k >> 3) << 4);
    int mt = o >> 4;
    int d = ((((chunk * 2 + ks2) * 4 + mt) * 2) * 64 + lane) * 8 + (k & 7);
    unsigned short* q = (unsigned short*)ws;
    float r1;
    unsigned short h = bfsplit(w1[i], r1);
    unsigned short m = bfsplit(r1, r1);
    q[d] = h; q[d + 512] = m;                 // plane stride = 64*8 = 512
    h = bfsplit(w2[i], r1); m = bfsplit(r1, r1);
    q[65536 + d] = h; q[65536 + d + 512] = m;
}

// -------- conv1x1 via MFMA v16: 16-px tiles -> 8 blocks/CU (TLP) -----------
// r13-r15 lesson: compiler sinks every reg prefetch (VGPR 60-72), so latency
// is exposed and only TLP can cover it; r13 had just 1.47 waves/SIMD.
// v16: block = 16-px tile x 64 out-ch, 4 waves (wave = 16oc x 16px, one MFMA
// subtile), LDS = 4KB X-frags + 16KB A-frags = 20KB -> 8 blocks/CU.
// Grid = 1500 blocks (4800/16*4 + 1200/16*4, exact) = 5.9 waves/SIMD.
// Same fragment layouts / staging math as r13 (verified); X read once.
__global__ __launch_bounds__(256) void conv_mfma(const float* __restrict__ f1,
                                                 const float* __restrict__ f2,
                                                 const float* __restrict__ b1v,
                                                 const float* __restrict__ b2v,
                                                 const float* __restrict__ wsbase,
                                                 float* __restrict__ c1o,
                                                 float* __restrict__ f2o) {
    __shared__ int xpl[1024];        // [ks2 2][plane2][lane64][word4] = 4KB
    __shared__ int alds[16 * 256];   // [ks2 2][mt4][plane2][lane64][word4] = 16KB
    int t = blockIdx.x;
    const float* X; const float* bias; float* Cout; const int* WPK;
    int P, px0;
    const unsigned short* q = (const unsigned short*)wsbase;
    if (t < 1200) {
        int b = t / 300, ti = t % 300;
        px0 = ti * 16;
        X = f1 + (size_t)b * CIN * P1;  P = P1;  bias = b1v;
        WPK = (const int*)q;
        Cout = c1o + (size_t)b * P1 * 64;
    } else {
        int u = t - 1200; int b = u / 75, ti = u % 75;
        px0 = ti * 16;
        X = f2 + (size_t)b * CIN * P2;  P = P2;  bias = b2v;
        WPK = (const int*)(q + 65536);
        Cout = f2o + (size_t)b * P2 * 64;
    }
    int tid  = threadIdx.x;
    int lane = tid & 63;
    int wv   = tid >> 6;              // compute mt
    int pcol = lane & 15;
    // staging: thread owns pixel px_s, channels cg*4..cg*4+3 of each chunk
    int px_s = tid & 15;
    int cg   = tid >> 4;              // 0..15
    int s_ks2 = cg >> 3;
    int s_lane = px_s + ((cg & 7) >> 1) * 16;   // px + 16*(k>>3)
    int s_w0   = (cg & 1) * 2;                  // word offset (k&7)>>1 base

    const float* Xg = X + px0 + px_s;

    float xvA[4], xvB[4];
    int4 areg[4];

    auto loadX = [&](float* dst, int cc) {
#pragma unroll
        for (int j = 0; j < 4; ++j)
            dst[j] = Xg[(size_t)(cc * 64 + cg * 4 + j) * P];
    };
    auto loadA = [&](int cc) {
#pragma unroll
        for (int p = 0; p < 4; ++p)
            areg[p] = *(const int4*)&WPK[cc * 4096 + p * 1024 + tid * 4];
    };
    auto stage = [&](const float* xs) {
        unsigned short h[4], m[4];
#pragma unroll
        for (int j = 0; j < 4; ++j) {
            float r;
            h[j] = bfsplit(xs[j], r);
            m[j] = bfsplit(r, r);
        }
        int vH0 = (int)h[0] | ((int)h[1] << 16);
        int vH1 = (int)h[2] | ((int)h[3] << 16);
        int vM0 = (int)m[0] | ((int)m[1] << 16);
        int vM1 = (int)m[2] | ((int)m[3] << 16);
        int bh = ((s_ks2 * 2 + 0) * 64 + s_lane) * 4 + s_w0;
        int bm = ((s_ks2 * 2 + 1) * 64 + s_lane) * 4 + s_w0;
        xpl[bh] = vH0; xpl[bh + 1] = vH1;
        xpl[bm] = vM0; xpl[bm + 1] = vM1;
#pragma unroll
        for (int p = 0; p < 4; ++p)
            *(int4*)&alds[p * 1024 + tid * 4] = areg[p];
    };

    union FU { int4 q; bf16x8 v; };
    f32x4 acc = (f32x4){0.f, 0.f, 0.f, 0.f};

    loadX(xvA, 0); loadA(0); stage(xvA); loadX(xvA, 1);
    __syncthreads();
    for (int c = 0; c < 8; ++c) {
        if (c < 7) loadA(c + 1);
        if (c < 6) loadX(xvB, c + 2);
#pragma unroll
        for (int ks2 = 0; ks2 < 2; ++ks2) {
            FU Ah, Am, Bh, Bm;
            int pa = ((ks2 * 4 + wv) * 2) * 256 + lane * 4;
            Ah.q = *(const int4*)&alds[pa];
            Am.q = *(const int4*)&alds[pa + 256];
            int pb = (ks2 * 2) * 256 + lane * 4;
            Bh.q = *(const int4*)&xpl[pb];
            Bm.q = *(const int4*)&xpl[pb + 256];
            acc = __builtin_amdgcn_mfma_f32_16x16x32_bf16(Ah.v, Bh.v, acc, 0, 0, 0);
            acc = __builtin_amdgcn_mfma_f32_16x16x32_bf16(Ah.v, Bm.v, acc, 0, 0, 0);
            acc = __builtin_amdgcn_mfma_f32_16x16x32_bf16(Am.v, Bh.v, acc, 0, 0, 0);
            acc = __builtin_amdgcn_mfma_f32_16x16x32_bf16(Am.v, Bm.v, acc, 0, 0, 0);
        }
        __syncthreads();
        if (c < 7) {
            stage(xvA);
            __syncthreads();
#pragma unroll
            for (int i2 = 0; i2 < 4; ++i2) xvA[i2] = xvB[i2];
        }
    }

    // epilogue: C/D col=lane&15 (pixel), row=(lane>>4)*4+reg (out-ch in mt)
    int r4 = (lane >> 4) * 4;
    float4 bb = *(const float4*)(bias + wv * 16 + r4);
    int px = px0 + pcol;
    float a0 = acc[0] + bb.x, a1 = acc[1] + bb.y;
    float a2 = acc[2] + bb.z, a3 = acc[3] + bb.w;
    *(float4*)(Cout + (size_t)px * 64 + wv * 16 + r4) =
        make_float4(a0 > 0.f ? a0 : 0.f, a1 > 0.f ? a1 : 0.f,
                    a2 > 0.f ? a2 : 0.f, a3 > 0.f ? a3 : 0.f);
}

// ---------------- head: add feat2-up, wo conv, softmax, argmax -> prb/seg ---
__global__ __launch_bounds__(256) void head_kernel(const float* __restrict__ wo,
                                                   const float* __restrict__ bo,
                                                   float* __restrict__ ws) {
    __shared__ float swo[NK * 64];
    __shared__ float sbo[NK];
    for (int i = threadIdx.x; i < NK * 64; i += 256) swo[i] = wo[i];
    if (threadIdx.x < NK) sbo[threadIdx.x] = bo[threadIdx.x];
    __syncthreads();

    int p  = blockIdx.x * 256 + threadIdx.x;   // 0..19199
    int b  = p / P1;
    int pb = p % P1;
    int y  = pb / W1p, x = pb % W1p;
    int qp = (y >> 1) * W2p + (x >> 1);
    const float* c1p = ws + WS_C1 + ((size_t)b * P1 + pb) * 64;
    const float* f2p = ws + WS_F2 + ((size_t)b * P2 + qp) * 64;

    float ok[NK];
#pragma unroll
    for (int k = 0; k < NK; ++k) ok[k] = sbo[k];
#pragma unroll
    for (int o4 = 0; o4 < 16; ++o4) {
        float4 c1q = *(const float4*)(c1p + o4 * 4);
        float4 f2q = *(const float4*)(f2p + o4 * 4);
        float co[4] = { c1q.x + f2q.x, c1q.y + f2q.y, c1q.z + f2q.z, c1q.w + f2q.w };
#pragma unroll
        for (int j = 0; j < 4; ++j) {
            int o = o4 * 4 + j;
#pragma unroll
            for (int k = 0; k < NK; ++k) ok[k] = fmaf(co[j], swo[k * 64 + o], ok[k]);
        }
    }
    float m = 0.f;
#pragma unroll
    for (int k = 0; k < NK; ++k) {
        ok[k] = ok[k] > 0.f ? ok[k] : 0.f;          // relu(out)
        if (ok[k] > m) m = ok[k];
    }
    float e[NK], sum = 0.f;
#pragma unroll
    for (int k = 0; k < NK; ++k) { e[k] = expf(ok[k] - m); sum += e[k]; }
    float inv = 1.f / sum;
    int arg = 0; float best = ok[0];
#pragma unroll
    for (int k = 1; k < NK; ++k) { if (ok[k] > best) { best = ok[k]; arg = k; } }

    float* pr = ws + WS_PRB + (size_t)p * 12;
#pragma unroll
    for (int k = 0; k < NK; ++k) pr[k] = e[k] * inv;
    pr[11] = (float)arg;
    ((int*)(ws + WS_SEG))[p] = arg;
}

// ---------------- upsample 8x: pure streaming replicate-store ----------------
__global__ __launch_bounds__(256) void upsample_kernel(const float* __restrict__ ws,
                                                       float* __restrict__ out) {
    const float* prb = ws + WS_PRB;
    unsigned total4 = (unsigned)((SEG_OFF + (size_t)NB * PLANE) / 4);  // 3,686,400
    unsigned step = gridDim.x * 256;
    for (unsigned i4 = blockIdx.x * 256 + threadIdx.x; i4 < total4; i4 += step) {
        unsigned f = i4 * 4;
        float v;
        if (f < (unsigned)SEG_OFF) {
            unsigned plane = f / (unsigned)PLANE;      // 0..43
            unsigned r = f - plane * (unsigned)PLANE;
            unsigned b = plane / NK, k = plane - b * NK;
            unsigned y = r / WOp, x = r - y * WOp;
            unsigned p = b * P1 + (y >> 3) * W1p + (x >> 3);
            v = prb[p * 12 + k];
        } else {
            unsigned g = f - (unsigned)SEG_OFF;
            unsigned b = g / (unsigned)PLANE;
            unsigned r = g - b * (unsigned)PLANE;
            unsigned y = r / WOp, x = r - y * WOp;
            unsigned p = b * P1 + (y >> 3) * W1p + (x >> 3);
            v = prb[p * 12 + 11];
        }
        *(float4*)(out + f) = make_float4(v, v, v, v);
    }
}

// ---------------- bbox: per-(batch,class) min/max/count over 60x80 seg ------
__global__ __launch_bounds__(256) void bbx_kernel(const float* __restrict__ ws,
                                                  float* __restrict__ out) {
    __shared__ int cnt[10], xmn[10], xmx[10], ymn[10], ymx[10];
    int b = blockIdx.x;
    int t = threadIdx.x;
    if (t < 10) { cnt[t] = 0; xmn[t] = 1 << 30; xmx[t] = -1; ymn[t] = 1 << 30; ymx[t] = -1; }
    __syncthreads();
    const int* seg = (const int*)(ws + WS_SEG) + b * P1;
    for (int p = t; p < P1; p += 256) {
        int s = seg[p];
        if (s >= 1 && s <= 9) {
            int y = p / W1p, x = p % W1p;
            atomicAdd(&cnt[s], 1);
            atomicMin(&xmn[s], x); atomicMax(&xmx[s], x);
            atomicMin(&ymn[s], y); atomicMax(&ymx[s], y);
        }
    }
    __syncthreads();
    if (t < 9) {
        int c = t + 1;
        bool valid = cnt[c] * 64 >= 500;    // upsampled count = 64*count
        float r[6];
        if (valid) {
            r[0] = (float)b;
            r[1] = (float)(xmn[c] * 8);
            r[2] = (float)(ymn[c] * 8);
            r[3] = (float)(xmx[c] * 8 + 7);
            r[4] = (float)(ymx[c] * 8 + 7);
            r[5] = (float)c;
        } else {
            for (int i = 0; i < 6; ++i) r[i] = -1.f;
        }
        float* row = out + BBX_OFF + (size_t)(b * 9 + t) * 6;
        for (int i = 0; i < 6; ++i) row[i] = r[i];
    }
}

extern "C" void kernel_launch(void* const* d_in, const int* in_sizes, int n_in,
                              void* d_out, int out_size, void* d_ws, size_t ws_size,
                              hipStream_t stream) {
    const float* f1 = (const float*)d_in[0];
    const float* f2 = (const float*)d_in[1];
    const float* w1 = (const float*)d_in[2];
    const float* b1 = (const float*)d_in[3];
    const float* w2 = (const float*)d_in[4];
    const float* b2 = (const float*)d_in[5];
    const float* wo = (const float*)d_in[6];
    const float* bo = (const float*)d_in[7];
    float* ws  = (float*)d_ws;
    float* out = (float*)d_out;

    pack_w<<<128, 256, 0, stream>>>(w1, w2, ws);
    conv_mfma<<<1500, 256, 0, stream>>>(f1, f2, b1, b2, ws,
                                        ws + WS_C1, ws + WS_F2);
    head_kernel<<<75, 256, 0, stream>>>(wo, bo, ws);
    upsample_kernel<<<2048, 256, 0, stream>>>(ws, out);
    bbx_kernel<<<NB, 256, 0, stream>>>(ws, out);
}

// Round 18
// 55.733 us; speedup vs baseline: 1.7662x; 1.7662x over previous
//
#include <hip/hip_runtime.h>
#include <math.h>

#define NB   4
#define CIN  512
#define HID  64
#define NK   11     // NUM_CLASSES+1
#define HH1  60
#define W1p  80
#define P1   4800
#define HH2  30
#define W2p  40
#define P2   1200
#define HO   480
#define WOp  640
#define NP1  (NB*P1)    // 19200
#define NP2  (NB*P2)    // 4800
#define PLANE ((size_t)HO*WOp)                  // 307200
#define SEG_OFF ((size_t)NB*NK*PLANE)           // 13,516,800
#define BBX_OFF (SEG_OFF + (size_t)NB*PLANE)    // 14,745,600

// ws layout in floats. Packed bf16 W-fragments: 2 convs x 2 planes x 32768
// ushort = 131072 ushort = 65536 floats.
#define WS_C1  65536                            // 19200*64 = 1,228,800
#define WS_F2  (WS_C1 + NP1*64)                 // 4800*64  =   307,200
#define WS_PRB (WS_F2 + NP2*64)                 // 19200*12 =   230,400
#define WS_SEG (WS_PRB + NP1*12)                // 19200 ints

typedef __attribute__((ext_vector_type(8))) short bf16x8;
typedef __attribute__((ext_vector_type(4))) float f32x4;

// RNE fp32 -> bf16, returns bits, writes residual x - bf16(x)
__device__ __forceinline__ unsigned short bfsplit(float x, float& resid) {
    unsigned u = __float_as_uint(x);
    unsigned t = u + 0x7FFFu + ((u >> 16) & 1u);
    unsigned short h = (unsigned short)(t >> 16);
    resid = x - __uint_as_float((unsigned)h << 16);
    return h;
}

// async global->LDS DMA, 16B per lane: lds dest = uniform base + lane*16
__device__ __forceinline__ void gld16(const void* g, void* l) {
    __builtin_amdgcn_global_load_lds(
        (const __attribute__((address_space(1))) void*)g,
        (__attribute__((address_space(3))) void*)l, 16, 0, 0);
}

// -------- pack weights into chunk-major A-fragment pages, 2-plane split -----
// (identical to r13, end-to-end verified at absmax 3.9e-3)
__global__ __launch_bounds__(256) void pack_w(const float* __restrict__ w1,
                                              const float* __restrict__ w2,
                                              float* __restrict__ ws) {
    int i = blockIdx.x * 256 + threadIdx.x;   // 0..32767
    if (i >= HID * CIN) return;
    int o = i >> 9, c = i & 511;
    int chunk = c >> 6, r = c & 63, ks2 = r >> 5, k = r & 31;
    int lane = (o & 15) + ((k >> 3) << 4);
    int mt = o >> 4;
    int d = ((((chunk * 2 + ks2) * 4 + mt) * 2) * 64 + lane) * 8 + (k & 7);
    unsigned short* q = (unsigned short*)ws;
    float r1;
    unsigned short h = bfsplit(w1[i], r1);
    unsigned short m = bfsplit(r1, r1);
    q[d] = h; q[d + 512] = m;                 // plane stride = 64*8 = 512
    h = bfsplit(w2[i], r1); m = bfsplit(r1, r1);
    q[65536 + d] = h; q[65536 + d + 512] = m;
}

// -------- conv1x1 via MFMA v18: async DMA staging (r13 geometry) ------------
// r12-r15 disease: hipcc sinks register prefetches (VGPR 60-72) -> exposed
// load latency at 1.5 waves/SIMD. v18 stages X (fp32 [ch][px]) and A (linear
// fragment pages) via global_load_lds 16B DMA -- unsinkable, zero VGPRs.
// Per chunk: {issue DMA c+1 | convert xraw[cur]->frags | lgkmcnt(0)+s_barrier
// (DMA STAYS IN FLIGHT) | MFMA | __syncthreads (drains DMA c+1)}.
// 376 blocks x 256 thr, 64-px tiles, 8 chunks of 64 ch. LDS 80KB.
__global__ __launch_bounds__(256) void conv_mfma(const float* __restrict__ f1,
                                                 const float* __restrict__ f2,
                                                 const float* __restrict__ b1v,
                                                 const float* __restrict__ b2v,
                                                 const float* __restrict__ wsbase,
                                                 float* __restrict__ c1o,
                                                 float* __restrict__ f2o) {
    __shared__ float xraw[2][4096];   // [buf][ch64][px64] fp32, 16KB each
    __shared__ int   alds[2][4096];   // [buf][linear A-frag page], 16KB each
    __shared__ int   xpl[4096];       // B-frags [pt4][ks2 2][plane2][lane64][w4]
    int t = blockIdx.x;
    const float* X; const float* bias; float* Cout; const int* WPK;
    int P, px0;
    const unsigned short* q = (const unsigned short*)wsbase;
    if (t < 300) {
        int b = t / 75, ti = t % 75;
        px0 = ti * 64;
        X = f1 + (size_t)b * CIN * P1;  P = P1;  bias = b1v;
        WPK = (const int*)q;
        Cout = c1o + (size_t)b * P1 * 64;
    } else {
        int u = t - 300; int b = u / 19, ti = u % 19;
        px0 = ti * 64; if (px0 > P2 - 64) px0 = P2 - 64;  // tail overlap benign
        X = f2 + (size_t)b * CIN * P2;  P = P2;  bias = b2v;
        WPK = (const int*)(q + 65536);
        Cout = f2o + (size_t)b * P2 * 64;
    }
    int tid  = threadIdx.x;
    int lane = tid & 63;
    int wv   = tid >> 6;              // staging pt AND compute mt
    int pcol = lane & 15, kgrp = lane >> 4;

    // DMA X: instr k (4/wave) covers chs 4k..4k+3, lane = (ch&3)<<4 | px-quad
    auto dmaX = [&](int cc, int buf) {
#pragma unroll
        for (int qq = 0; qq < 4; ++qq) {
            int k = wv * 4 + qq;
            const float* g = X + (size_t)(cc * 64 + k * 4 + (lane >> 4)) * P
                           + px0 + (lane & 15) * 4;
            gld16(g, (void*)&xraw[buf][k * 256]);
        }
    };
    // DMA A: linear 16KB page copy (already in fragment order from pack_w)
    auto dmaA = [&](int cc, int buf) {
#pragma unroll
        for (int qq = 0; qq < 4; ++qq) {
            int k = wv * 4 + qq;
            const int* g = WPK + cc * 4096 + k * 256 + lane * 4;
            gld16(g, (void*)&alds[buf][k * 256]);
        }
    };
    // convert: thread owns pixel wv*16+pcol, chs ks2*32+kgrp*8+j (r13 mapping)
    auto convert = [&](int buf) {
        int pxl = wv * 16 + pcol;
#pragma unroll
        for (int ks2 = 0; ks2 < 2; ++ks2) {
            int hh[8], mm[8];
#pragma unroll
            for (int j = 0; j < 8; ++j) {
                float x = xraw[buf][(ks2 * 32 + kgrp * 8 + j) * 64 + pxl];
                float r;
                unsigned short h = bfsplit(x, r);
                unsigned short m = bfsplit(r, r);
                hh[j] = h; mm[j] = m;
            }
            int4 H, M;
            ((int*)&H)[0] = hh[0] | (hh[1] << 16); ((int*)&H)[1] = hh[2] | (hh[3] << 16);
            ((int*)&H)[2] = hh[4] | (hh[5] << 16); ((int*)&H)[3] = hh[6] | (hh[7] << 16);
            ((int*)&M)[0] = mm[0] | (mm[1] << 16); ((int*)&M)[1] = mm[2] | (mm[3] << 16);
            ((int*)&M)[2] = mm[4] | (mm[5] << 16); ((int*)&M)[3] = mm[6] | (mm[7] << 16);
            int pg = ((wv * 2 + ks2) * 2) * 256 + lane * 4;
            *(int4*)&xpl[pg]       = H;
            *(int4*)&xpl[pg + 256] = M;
        }
    };

    union FU { int4 q; bf16x8 v; };
    f32x4 acc[4];
#pragma unroll
    for (int st = 0; st < 4; ++st) acc[st] = (f32x4){0.f, 0.f, 0.f, 0.f};

    // prologue: chunk 0 DMA, full drain
    dmaX(0, 0); dmaA(0, 0);
    __syncthreads();

    int cur = 0;
    for (int c = 0; c < 8; ++c) {
        if (c < 7) { dmaX(c + 1, cur ^ 1); dmaA(c + 1, cur ^ 1); }
        convert(cur);
        // frag-writes visible to all waves; DO NOT drain vmcnt (DMA in flight)
        asm volatile("s_waitcnt lgkmcnt(0)" ::: "memory");
        __builtin_amdgcn_s_barrier();
        __builtin_amdgcn_sched_barrier(0);
#pragma unroll
        for (int ks2 = 0; ks2 < 2; ++ks2) {
            FU Ah, Am;
            int pa = ((ks2 * 4 + wv) * 2) * 256 + lane * 4;
            Ah.q = *(const int4*)&alds[cur][pa];
            Am.q = *(const int4*)&alds[cur][pa + 256];
#pragma unroll
            for (int st = 0; st < 4; ++st) {
                FU Bh, Bm;
                int pb = ((st * 2 + ks2) * 2) * 256 + lane * 4;
                Bh.q = *(const int4*)&xpl[pb];
                Bm.q = *(const int4*)&xpl[pb + 256];
                acc[st] = __builtin_amdgcn_mfma_f32_16x16x32_bf16(Ah.v, Bh.v, acc[st], 0, 0, 0);
                acc[st] = __builtin_amdgcn_mfma_f32_16x16x32_bf16(Ah.v, Bm.v, acc[st], 0, 0, 0);
                acc[st] = __builtin_amdgcn_mfma_f32_16x16x32_bf16(Am.v, Bh.v, acc[st], 0, 0, 0);
                acc[st] = __builtin_amdgcn_mfma_f32_16x16x32_bf16(Am.v, Bm.v, acc[st], 0, 0, 0);
            }
        }
        __builtin_amdgcn_sched_barrier(0);
        __syncthreads();    // drains vmcnt (DMA c+1 landed) + lgkm, barrier
        cur ^= 1;
    }

    // epilogue: C/D layout col=lane&15 (px-in-st), row=(lane>>4)*4+reg (out-ch)
    int r4 = (lane >> 4) * 4;
    float4 bb = *(const float4*)(bias + wv * 16 + r4);
#pragma unroll
    for (int st = 0; st < 4; ++st) {
        int px = px0 + st * 16 + pcol;
        float a0 = acc[st][0] + bb.x;
        float a1 = acc[st][1] + bb.y;
        float a2 = acc[st][2] + bb.z;
        float a3 = acc[st][3] + bb.w;
        *(float4*)(Cout + (size_t)px * 64 + wv * 16 + r4) =
            make_float4(a0 > 0.f ? a0 : 0.f, a1 > 0.f ? a1 : 0.f,
                        a2 > 0.f ? a2 : 0.f, a3 > 0.f ? a3 : 0.f);
    }
}

// ---------------- head: add feat2-up, wo conv, softmax, argmax -> prb/seg ---
__global__ __launch_bounds__(256) void head_kernel(const float* __restrict__ wo,
                                                   const float* __restrict__ bo,
                                                   float* __restrict__ ws) {
    __shared__ float swo[NK * 64];
    __shared__ float sbo[NK];
    for (int i = threadIdx.x; i < NK * 64; i += 256) swo[i] = wo[i];
    if (threadIdx.x < NK) sbo[threadIdx.x] = bo[threadIdx.x];
    __syncthreads();

    int p  = blockIdx.x * 256 + threadIdx.x;   // 0..19199
    int b  = p / P1;
    int pb = p % P1;
    int y  = pb / W1p, x = pb % W1p;
    int qp = (y >> 1) * W2p + (x >> 1);
    const float* c1p = ws + WS_C1 + ((size_t)b * P1 + pb) * 64;
    const float* f2p = ws + WS_F2 + ((size_t)b * P2 + qp) * 64;

    float ok[NK];
#pragma unroll
    for (int k = 0; k < NK; ++k) ok[k] = sbo[k];
#pragma unroll
    for (int o4 = 0; o4 < 16; ++o4) {
        float4 c1q = *(const float4*)(c1p + o4 * 4);
        float4 f2q = *(const float4*)(f2p + o4 * 4);
        float co[4] = { c1q.x + f2q.x, c1q.y + f2q.y, c1q.z + f2q.z, c1q.w + f2q.w };
#pragma unroll
        for (int j = 0; j < 4; ++j) {
            int o = o4 * 4 + j;
#pragma unroll
            for (int k = 0; k < NK; ++k) ok[k] = fmaf(co[j], swo[k * 64 + o], ok[k]);
        }
    }
    float m = 0.f;
#pragma unroll
    for (int k = 0; k < NK; ++k) {
        ok[k] = ok[k] > 0.f ? ok[k] : 0.f;          // relu(out)
        if (ok[k] > m) m = ok[k];
    }
    float e[NK], sum = 0.f;
#pragma unroll
    for (int k = 0; k < NK; ++k) { e[k] = expf(ok[k] - m); sum += e[k]; }
    float inv = 1.f / sum;
    int arg = 0; float best = ok[0];
#pragma unroll
    for (int k = 1; k < NK; ++k) { if (ok[k] > best) { best = ok[k]; arg = k; } }

    float* pr = ws + WS_PRB + (size_t)p * 12;
#pragma unroll
    for (int k = 0; k < NK; ++k) pr[k] = e[k] * inv;
    pr[11] = (float)arg;
    ((int*)(ws + WS_SEG))[p] = arg;
}

// ---------------- upsample 8x: pure streaming replicate-store ----------------
__global__ __launch_bounds__(256) void upsample_kernel(const float* __restrict__ ws,
                                                       float* __restrict__ out) {
    const float* prb = ws + WS_PRB;
    unsigned total4 = (unsigned)((SEG_OFF + (size_t)NB * PLANE) / 4);  // 3,686,400
    unsigned step = gridDim.x * 256;
    for (unsigned i4 = blockIdx.x * 256 + threadIdx.x; i4 < total4; i4 += step) {
        unsigned f = i4 * 4;
        float v;
        if (f < (unsigned)SEG_OFF) {
            unsigned plane = f / (unsigned)PLANE;      // 0..43
            unsigned r = f - plane * (unsigned)PLANE;
            unsigned b = plane / NK, k = plane - b * NK;
            unsigned y = r / WOp, x = r - y * WOp;
            unsigned p = b * P1 + (y >> 3) * W1p + (x >> 3);
            v = prb[p * 12 + k];
        } else {
            unsigned g = f - (unsigned)SEG_OFF;
            unsigned b = g / (unsigned)PLANE;
            unsigned r = g - b * (unsigned)PLANE;
            unsigned y = r / WOp, x = r - y * WOp;
            unsigned p = b * P1 + (y >> 3) * W1p + (x >> 3);
            v = prb[p * 12 + 11];
        }
        *(float4*)(out + f) = make_float4(v, v, v, v);
    }
}

// ---------------- bbox: per-(batch,class) min/max/count over 60x80 seg ------
__global__ __launch_bounds__(256) void bbx_kernel(const float* __restrict__ ws,
                                                  float* __restrict__ out) {
    __shared__ int cnt[10], xmn[10], xmx[10], ymn[10], ymx[10];
    int b = blockIdx.x;
    int t = threadIdx.x;
    if (t < 10) { cnt[t] = 0; xmn[t] = 1 << 30; xmx[t] = -1; ymn[t] = 1 << 30; ymx[t] = -1; }
    __syncthreads();
    const int* seg = (const int*)(ws + WS_SEG) + b * P1;
    for (int p = t; p < P1; p += 256) {
        int s = seg[p];
        if (s >= 1 && s <= 9) {
            int y = p / W1p, x = p % W1p;
            atomicAdd(&cnt[s], 1);
            atomicMin(&xmn[s], x); atomicMax(&xmx[s], x);
            atomicMin(&ymn[s], y); atomicMax(&ymx[s], y);
        }
    }
    __syncthreads();
    if (t < 9) {
        int c = t + 1;
        bool valid = cnt[c] * 64 >= 500;    // upsampled count = 64*count
        float r[6];
        if (valid) {
            r[0] = (float)b;
            r[1] = (float)(xmn[c] * 8);
            r[2] = (float)(ymn[c] * 8);
            r[3] = (float)(xmx[c] * 8 + 7);
            r[4] = (float)(ymx[c] * 8 + 7);
            r[5] = (float)c;
        } else {
            for (int i = 0; i < 6; ++i) r[i] = -1.f;
        }
        float* row = out + BBX_OFF + (size_t)(b * 9 + t) * 6;
        for (int i = 0; i < 6; ++i) row[i] = r[i];
    }
}

extern "C" void kernel_launch(void* const* d_in, const int* in_sizes, int n_in,
                              void* d_out, int out_size, void* d_ws, size_t ws_size,
                              hipStream_t stream) {
    const float* f1 = (const float*)d_in[0];
    const float* f2 = (const float*)d_in[1];
    const float* w1 = (const float*)d_in[2];
    const float* b1 = (const float*)d_in[3];
    const float* w2 = (const float*)d_in[4];
    const float* b2 = (const float*)d_in[5];
    const float* wo = (const float*)d_in[6];
    const float* bo = (const float*)d_in[7];
    float* ws  = (float*)d_ws;
    float* out = (float*)d_out;

    pack_w<<<128, 256, 0, stream>>>(w1, w2, ws);
    conv_mfma<<<376, 256, 0, stream>>>(f1, f2, b1, b2, ws,
                                       ws + WS_C1, ws + WS_F2);
    head_kernel<<<75, 256, 0, stream>>>(wo, bo, ws);
    upsample_kernel<<<2048, 256, 0, stream>>>(ws, out);
    bbx_kernel<<<NB, 256, 0, stream>>>(ws, out);
}